// Round 7
// baseline (54.341 us; speedup 1.0000x reference)
//
#include <hip/hip_runtime.h>
#include <hip/hip_bf16.h>

typedef __attribute__((ext_vector_type(4)))  float f32x4;
typedef __attribute__((ext_vector_type(16))) float f32x16;
typedef __attribute__((ext_vector_type(8)))  short bf16x8;
typedef __attribute__((ext_vector_type(4)))  unsigned u32x4;
typedef __attribute__((ext_vector_type(2)))  unsigned u32x2;

#define NEG_INF_F (-1000000000.0f)

// native bf16 RNE converts -> compiler emits v_cvt_pk_bf16_f32
__device__ inline unsigned pkbf(float a, float b) {
    union { __hip_bfloat16 h; unsigned short u; } x, y;
    x.h = __float2bfloat16(a);
    y.h = __float2bfloat16(b);
    return (unsigned)x.u | ((unsigned)y.u << 16);
}

// R7: 4-warp (256-thr) blocks, 128 q-rows each; grid (64 bh, 8 qt) = 512 blocks
//     = 2 independent blocks/CU (vs 1 barrier-coupled block in R6) -> stall overlap.
// mfma_f32_32x32x16_bf16:
//   A[m][k]: m=lane&31, k=(lane>>5)*8+j ; B[k][n]: n=lane&31, k=(lane>>5)*8+j
//   C[m][n]: n=lane&31, m=crow(r,h)=(r&3)+8*(r>>2)+4*(lane>>5)
// QK^T swapped -> lane holds q, 32 keys in regs; softmax in-lane;
// P via cvt_pk + permlane32_swap (T12); PV B-operand from transposed Vt LDS;
// double-buffered K/Vt, loads at top of iter, ds_write at tail (T14); setprio (T5).
__global__ __launch_bounds__(256) void aoa_attn_kernel(
    const float* __restrict__ gv,
    const float* __restrict__ q2,
    const float* __restrict__ keyp,
    const int*   __restrict__ maskp,
    const float* __restrict__ v1,
    const float* __restrict__ v2,
    const float* __restrict__ W,
    const float* __restrict__ bch,
    float* __restrict__ out)
{
    constexpr int S = 1024, D = 64;
    const int bh  = blockIdx.x;
    const int qt  = blockIdx.y;   // 0..7
    const int b   = bh >> 3;
    const int tid = threadIdx.x;
    const int wid = tid >> 6;     // 0..3
    const int lane = tid & 63;
    const int l31 = lane & 31;
    const int h   = lane >> 5;

    float* out_attn = out + 512;
    if (bh == 0 && qt == 0) { out[tid] = gv[tid]; out[tid + 256] = gv[tid + 256]; }

    __shared__ float maskf[S];             // 0 or NEG_INF
    __shared__ short Klds[2][64][72];      // [buf][key][d], 144B stride
    __shared__ short Vt[2][64][72];        // [buf][d][key]
    __shared__ float Lw[4][32];            // per-warp 1/l per q

    for (int i = tid; i < S; i += 256)
        maskf[i] = maskp[b * S + i] ? 0.0f : NEG_INF_F;

    const size_t base = (size_t)bh * S * D;
    const float* Qp  = q2   + base;
    const float* Kp  = keyp + base;
    const float* V1p = v1   + base;
    const float* V2p = v2   + base;

    const int q0   = qt * 128 + wid * 32;
    const int qrow = q0 + l31;

    // Q B-fragments: bq[ds][j] = Q[qrow][ds*16 + h*8 + j]
    bf16x8 bq[4];
    #pragma unroll
    for (int ds = 0; ds < 4; ++ds) {
        const f32x4* p = (const f32x4*)(Qp + (size_t)qrow * D + ds * 16 + h * 8);
        f32x4 x0 = p[0], x1 = p[1];
        u32x4 u = (u32x4){pkbf(x0[0], x0[1]), pkbf(x0[2], x0[3]),
                          pkbf(x1[0], x1[1]), pkbf(x1[2], x1[3])};
        bq[ds] = *(bf16x8*)&u;
    }

    f32x16 acc_o[2];
    #pragma unroll
    for (int dh = 0; dh < 2; ++dh)
        #pragma unroll
        for (int r = 0; r < 16; ++r) acc_o[dh][r] = 0.0f;

    float m_run = -1e30f, l_run = 0.0f;
    const float SC = 0.125f * 1.4426950408889634f;   // D^-0.5 * log2(e)

    // staging indices (256 threads)
    const int kk   = tid >> 2;           // K row 0..63
    const int d0   = (tid & 3) << 4;     // K d-offset {0,16,32,48}
    const int dcol = tid & 63;           // Vt d-column
    const int kr0  = (tid >> 6) << 4;    // Vt key chunk {0,16,32,48}

    // prologue: tile 0 -> regs -> buf 0
    f32x4 kA0, kA1, kA2, kA3;
    float vv[16];
    {
        const f32x4* src = (const f32x4*)(Kp + (size_t)kk * D + d0);
        kA0 = src[0]; kA1 = src[1]; kA2 = src[2]; kA3 = src[3];
        #pragma unroll
        for (int i = 0; i < 16; ++i) vv[i] = V2p[(size_t)(kr0 + i) * D + dcol];
    }
    *(u32x4*)&Klds[0][kk][d0] = (u32x4){pkbf(kA0[0], kA0[1]), pkbf(kA0[2], kA0[3]),
                                        pkbf(kA1[0], kA1[1]), pkbf(kA1[2], kA1[3])};
    *(u32x4*)&Klds[0][kk][d0 + 8] = (u32x4){pkbf(kA2[0], kA2[1]), pkbf(kA2[2], kA2[3]),
                                            pkbf(kA3[0], kA3[1]), pkbf(kA3[2], kA3[3])};
    *(u32x4*)&Vt[0][dcol][kr0] = (u32x4){pkbf(vv[0], vv[1]), pkbf(vv[2], vv[3]),
                                         pkbf(vv[4], vv[5]), pkbf(vv[6], vv[7])};
    *(u32x4*)&Vt[0][dcol][kr0 + 8] = (u32x4){pkbf(vv[8], vv[9]), pkbf(vv[10], vv[11]),
                                             pkbf(vv[12], vv[13]), pkbf(vv[14], vv[15])};
    int cur = 0;

    for (int t = 0; t < 16; ++t) {
        const int kt = t * 64;
        __syncthreads();   // buf[cur] visible; buf[cur^1] free

        if (t < 15) {   // issue next tile's loads; land under compute
            const f32x4* src = (const f32x4*)(Kp + (size_t)(kt + 64 + kk) * D + d0);
            kA0 = src[0]; kA1 = src[1]; kA2 = src[2]; kA3 = src[3];
            #pragma unroll
            for (int i = 0; i < 16; ++i) vv[i] = V2p[(size_t)(kt + 64 + kr0 + i) * D + dcol];
        }

        // ---- QK^T: S^T[key][q], 2 subtiles of 32 keys ----
        f32x16 accs[2];
        __builtin_amdgcn_s_setprio(1);
        #pragma unroll
        for (int sub = 0; sub < 2; ++sub) {
            f32x16 a;
            #pragma unroll
            for (int r = 0; r < 16; ++r) a[r] = 0.0f;
            #pragma unroll
            for (int ds = 0; ds < 4; ++ds) {
                bf16x8 ak = *(const bf16x8*)&Klds[cur][sub * 32 + l31][ds * 16 + h * 8];
                a = __builtin_amdgcn_mfma_f32_32x32x16_bf16(ak, bq[ds], a, 0, 0, 0);
            }
            accs[sub] = a;
        }
        __builtin_amdgcn_s_setprio(0);

        // ---- mask + scale + in-lane online softmax (32 keys/lane) ----
        float s[32];
        float tmax = -1e30f;
        #pragma unroll
        for (int sub = 0; sub < 2; ++sub)
            #pragma unroll
            for (int g = 0; g < 4; ++g) {
                f32x4 mk = *(const f32x4*)&maskf[kt + sub * 32 + g * 8 + h * 4];
                #pragma unroll
                for (int j = 0; j < 4; ++j) {
                    float val = fmaf(accs[sub][g * 4 + j], SC, mk[j]);
                    s[sub * 16 + g * 4 + j] = val;
                    tmax = fmaxf(tmax, val);
                }
            }
        tmax = fmaxf(tmax, __shfl_xor(tmax, 32));

        if (__any(tmax > m_run + 8.0f)) {   // defer-max (T13)
            float mnew = fmaxf(m_run, tmax);
            float r = __builtin_amdgcn_exp2f(m_run - mnew);
            l_run *= r;
            #pragma unroll
            for (int dh = 0; dh < 2; ++dh)
                #pragma unroll
                for (int r2 = 0; r2 < 16; ++r2) acc_o[dh][r2] *= r;
            m_run = mnew;
        }

        float psum = 0.0f;
        unsigned w[16];
        #pragma unroll
        for (int i = 0; i < 16; ++i) {
            float p0 = __builtin_amdgcn_exp2f(s[2 * i]     - m_run);
            float p1 = __builtin_amdgcn_exp2f(s[2 * i + 1] - m_run);
            psum += p0 + p1;
            w[i] = pkbf(p0, p1);
        }
        psum += __shfl_xor(psum, 32);
        l_run += psum;

        // ---- PV: O[q][d] += P x Vt ----
        __builtin_amdgcn_s_setprio(1);
        #pragma unroll
        for (int sub = 0; sub < 2; ++sub) {
            #pragma unroll
            for (int t2 = 0; t2 < 2; ++t2) {
                const int wb = sub * 8 + t2 * 4;
                u32x2 r0 = __builtin_amdgcn_permlane32_swap(w[wb + 0], w[wb + 2], false, false);
                u32x2 r1 = __builtin_amdgcn_permlane32_swap(w[wb + 1], w[wb + 3], false, false);
                u32x4 ua = (u32x4){r0[0], r1[0], r0[1], r1[1]};
                bf16x8 pa = *(bf16x8*)&ua;
                #pragma unroll
                for (int dh = 0; dh < 2; ++dh) {
                    bf16x8 bv = *(const bf16x8*)&Vt[cur][dh * 32 + l31][sub * 32 + t2 * 16 + h * 8];
                    acc_o[dh] = __builtin_amdgcn_mfma_f32_32x32x16_bf16(pa, bv, acc_o[dh], 0, 0, 0);
                }
            }
        }
        __builtin_amdgcn_s_setprio(0);

        if (t < 15) {   // write next tile into alternate buffer
            *(u32x4*)&Klds[cur ^ 1][kk][d0] = (u32x4){pkbf(kA0[0], kA0[1]), pkbf(kA0[2], kA0[3]),
                                                      pkbf(kA1[0], kA1[1]), pkbf(kA1[2], kA1[3])};
            *(u32x4*)&Klds[cur ^ 1][kk][d0 + 8] = (u32x4){pkbf(kA2[0], kA2[1]), pkbf(kA2[2], kA2[3]),
                                                          pkbf(kA3[0], kA3[1]), pkbf(kA3[2], kA3[3])};
            *(u32x4*)&Vt[cur ^ 1][dcol][kr0] = (u32x4){pkbf(vv[0], vv[1]), pkbf(vv[2], vv[3]),
                                                       pkbf(vv[4], vv[5]), pkbf(vv[6], vv[7])};
            *(u32x4*)&Vt[cur ^ 1][dcol][kr0 + 8] = (u32x4){pkbf(vv[8], vv[9]), pkbf(vv[10], vv[11]),
                                                           pkbf(vv[12], vv[13]), pkbf(vv[14], vv[15])};
        }
        cur ^= 1;
    }

    // ---- channel gate: gate[q][e] = sum_d am[q][d]*W[e][d], same C layout as O ----
    f32x16 acc_g[2];
    #pragma unroll
    for (int eh = 0; eh < 2; ++eh)
        #pragma unroll
        for (int r = 0; r < 16; ++r) acc_g[eh][r] = 0.0f;

    bf16x8 bam[4];
    #pragma unroll
    for (int ds = 0; ds < 4; ++ds) {
        const f32x4* p1 = (const f32x4*)(V1p + (size_t)qrow * D + ds * 16 + h * 8);
        const f32x4* pk = (const f32x4*)(Kp  + (size_t)qrow * D + ds * 16 + h * 8);
        f32x4 a0 = p1[0], a1 = p1[1], c0 = pk[0], c1 = pk[1];
        u32x4 u = (u32x4){pkbf(a0[0] * c0[0], a0[1] * c0[1]), pkbf(a0[2] * c0[2], a0[3] * c0[3]),
                          pkbf(a1[0] * c1[0], a1[1] * c1[1]), pkbf(a1[2] * c1[2], a1[3] * c1[3])};
        bam[ds] = *(bf16x8*)&u;
    }
    #pragma unroll
    for (int eh = 0; eh < 2; ++eh) {
        #pragma unroll
        for (int ds = 0; ds < 4; ++ds) {
            const f32x4* pw = (const f32x4*)(W + (size_t)(eh * 32 + l31) * D + ds * 16 + h * 8);
            f32x4 x0 = pw[0], x1 = pw[1];
            u32x4 u = (u32x4){pkbf(x0[0], x0[1]), pkbf(x0[2], x0[3]),
                              pkbf(x1[0], x1[1]), pkbf(x1[2], x1[3])};
            bf16x8 bw = *(bf16x8*)&u;
            acc_g[eh] = __builtin_amdgcn_mfma_f32_32x32x16_bf16(bam[ds], bw, acc_g[eh], 0, 0, 0);
        }
    }

    // ---- epilogue: out = (O/l) * sigmoid(gate + b) ----
    Lw[wid][l31] = 1.0f / l_run;
    __builtin_amdgcn_wave_barrier();
    const float bv0 = bch[l31], bv1 = bch[32 + l31];
    #pragma unroll
    for (int dh = 0; dh < 2; ++dh) {
        const float bc = dh ? bv1 : bv0;
        #pragma unroll
        for (int r = 0; r < 16; ++r) {
            const int ql = (r & 3) + 8 * (r >> 2) + 4 * h;   // crow(r,h)
            float invl = Lw[wid][ql];
            float o = acc_o[dh][r] * invl;
            float z = acc_g[dh][r] + bc;
            float gate = 1.0f / (1.0f + __expf(-z));
            out_attn[base + (size_t)(q0 + ql) * D + dh * 32 + l31] = o * gate;
        }
    }
}

extern "C" void kernel_launch(void* const* d_in, const int* in_sizes, int n_in,
                              void* d_out, int out_size, void* d_ws, size_t ws_size,
                              hipStream_t stream) {
    const float* gv   = (const float*)d_in[0];
    const float* q2   = (const float*)d_in[1];
    const float* keyp = (const float*)d_in[2];
    const int*   mask = (const int*)  d_in[3];
    const float* v1   = (const float*)d_in[4];
    const float* v2   = (const float*)d_in[5];
    const float* W    = (const float*)d_in[6];
    const float* bch  = (const float*)d_in[7];
    float* out = (float*)d_out;

    dim3 grid(64, 8);   // (b*h, 128-row q-tile) = 512 blocks = 2/CU
    aoa_attn_kernel<<<grid, 256, 0, stream>>>(gv, q2, keyp, mask, v1, v2, W, bch, out);
}

// Round 8
// 46.928 us; speedup vs baseline: 1.1580x; 1.1580x over previous
//
#include <hip/hip_runtime.h>
#include <hip/hip_bf16.h>

typedef __attribute__((ext_vector_type(4)))  float f32x4;
typedef __attribute__((ext_vector_type(16))) float f32x16;
typedef __attribute__((ext_vector_type(8)))  short bf16x8;
typedef __attribute__((ext_vector_type(4)))  unsigned u32x4;
typedef __attribute__((ext_vector_type(2)))  unsigned u32x2;

#define NEG_INF_F (-1000000000.0f)

// native bf16 RNE converts -> compiler emits v_cvt_pk_bf16_f32
__device__ inline unsigned pkbf(float a, float b) {
    union { __hip_bfloat16 h; unsigned short u; } x, y;
    x.h = __float2bfloat16(a);
    y.h = __float2bfloat16(b);
    return (unsigned)x.u | ((unsigned)y.u << 16);
}

// R8 = R6 base (8 warps x 32 q = 256 q/block, grid (64,4) = 1 block/CU,
//      double-buffered K/Vt, 1 barrier/tile) + intra-tile half-pipelining:
//      QK(h1) issued before SM(h0), SM(h1) between PV(h0) and PV(h1) ->
//      MFMA pipe overlaps VALU softmax within each wave (T15-lite).
// mfma_f32_32x32x16_bf16:
//   A[m][k]: m=lane&31, k=(lane>>5)*8+j ; B[k][n]: n=lane&31, k=(lane>>5)*8+j
//   C[m][n]: n=lane&31, m=crow(r,h)=(r&3)+8*(r>>2)+4*(lane>>5)
__global__ __launch_bounds__(512) void aoa_attn_kernel(
    const float* __restrict__ gv,
    const float* __restrict__ q2,
    const float* __restrict__ keyp,
    const int*   __restrict__ maskp,
    const float* __restrict__ v1,
    const float* __restrict__ v2,
    const float* __restrict__ W,
    const float* __restrict__ bch,
    float* __restrict__ out)
{
    constexpr int S = 1024, D = 64;
    const int bh  = blockIdx.x;
    const int qt  = blockIdx.y;
    const int b   = bh >> 3;
    const int tid = threadIdx.x;
    const int wid = tid >> 6;
    const int lane = tid & 63;
    const int l31 = lane & 31;
    const int h   = lane >> 5;

    float* out_attn = out + 512;
    if (bh == 0 && qt == 0) out[tid] = gv[tid];

    __shared__ float maskf[S];             // 0 or NEG_INF
    __shared__ short Klds[2][64][72];      // [buf][key][d], 144B stride
    __shared__ short Vt[2][64][72];        // [buf][d][key]
    __shared__ float Lw[8][32];            // per-warp 1/l per q

    for (int i = tid; i < S; i += 512)
        maskf[i] = maskp[b * S + i] ? 0.0f : NEG_INF_F;

    const size_t base = (size_t)bh * S * D;
    const float* Qp  = q2   + base;
    const float* Kp  = keyp + base;
    const float* V1p = v1   + base;
    const float* V2p = v2   + base;

    const int q0   = qt * 256 + wid * 32;
    const int qrow = q0 + l31;

    // Q B-fragments: bq[ds][j] = Q[qrow][ds*16 + h*8 + j]
    bf16x8 bq[4];
    #pragma unroll
    for (int ds = 0; ds < 4; ++ds) {
        const f32x4* p = (const f32x4*)(Qp + (size_t)qrow * D + ds * 16 + h * 8);
        f32x4 x0 = p[0], x1 = p[1];
        u32x4 u = (u32x4){pkbf(x0[0], x0[1]), pkbf(x0[2], x0[3]),
                          pkbf(x1[0], x1[1]), pkbf(x1[2], x1[3])};
        bq[ds] = *(bf16x8*)&u;
    }

    f32x16 acc_o[2];
    #pragma unroll
    for (int dh = 0; dh < 2; ++dh)
        #pragma unroll
        for (int r = 0; r < 16; ++r) acc_o[dh][r] = 0.0f;

    float m_run = -1e30f, l_run = 0.0f;
    const float SC = 0.125f * 1.4426950408889634f;   // D^-0.5 * log2(e)

    // staging indices (512 threads)
    const int kk   = tid >> 3;          // K row 0..63
    const int d0   = (tid & 7) << 3;    // K d-offset
    const int dcol = tid & 63;          // Vt d-column
    const int kr0  = (tid >> 6) << 3;   // Vt key chunk = wid*8

    // prologue: tile 0 -> regs -> buf 0
    f32x4 kA, kB;
    float vv[8];
    {
        const f32x4* src = (const f32x4*)(Kp + (size_t)kk * D + d0);
        kA = src[0]; kB = src[1];
        #pragma unroll
        for (int i = 0; i < 8; ++i) vv[i] = V2p[(size_t)(kr0 + i) * D + dcol];
    }
    *(u32x4*)&Klds[0][kk][d0] = (u32x4){pkbf(kA[0], kA[1]), pkbf(kA[2], kA[3]),
                                        pkbf(kB[0], kB[1]), pkbf(kB[2], kB[3])};
    *(u32x4*)&Vt[0][dcol][kr0] = (u32x4){pkbf(vv[0], vv[1]), pkbf(vv[2], vv[3]),
                                         pkbf(vv[4], vv[5]), pkbf(vv[6], vv[7])};
    int cur = 0;

    for (int t = 0; t < 16; ++t) {
        const int kt = t * 64;
        __syncthreads();   // buf[cur] visible; buf[cur^1] free

        if (t < 15) {   // issue next tile's loads; land under compute
            const f32x4* src = (const f32x4*)(Kp + (size_t)(kt + 64 + kk) * D + d0);
            kA = src[0]; kB = src[1];
            #pragma unroll
            for (int i = 0; i < 8; ++i) vv[i] = V2p[(size_t)(kt + 64 + kr0 + i) * D + dcol];
        }

        // ---- QK^T half 0 (keys kt+0..31) ----
        f32x16 a0;
        #pragma unroll
        for (int r = 0; r < 16; ++r) a0[r] = 0.0f;
        #pragma unroll
        for (int ds = 0; ds < 4; ++ds) {
            bf16x8 ak = *(const bf16x8*)&Klds[cur][l31][ds * 16 + h * 8];
            a0 = __builtin_amdgcn_mfma_f32_32x32x16_bf16(ak, bq[ds], a0, 0, 0, 0);
        }
        // ---- QK^T half 1 (keys kt+32..63) — issued BEFORE softmax(h0) ----
        f32x16 a1;
        #pragma unroll
        for (int r = 0; r < 16; ++r) a1[r] = 0.0f;
        #pragma unroll
        for (int ds = 0; ds < 4; ++ds) {
            bf16x8 ak = *(const bf16x8*)&Klds[cur][32 + l31][ds * 16 + h * 8];
            a1 = __builtin_amdgcn_mfma_f32_32x32x16_bf16(ak, bq[ds], a1, 0, 0, 0);
        }

        // ---- softmax half 0 (VALU; overlaps QK h1 MFMA latency) ----
        unsigned w0[8];
        {
            float s[16];
            float tmax = -1e30f;
            #pragma unroll
            for (int g = 0; g < 4; ++g) {
                f32x4 mk = *(const f32x4*)&maskf[kt + g * 8 + h * 4];
                #pragma unroll
                for (int j = 0; j < 4; ++j) {
                    float val = fmaf(a0[g * 4 + j], SC, mk[j]);
                    s[g * 4 + j] = val;
                    tmax = fmaxf(tmax, val);
                }
            }
            tmax = fmaxf(tmax, __shfl_xor(tmax, 32));
            if (__any(tmax > m_run + 8.0f)) {   // defer-max (T13)
                float mnew = fmaxf(m_run, tmax);
                float r = __builtin_amdgcn_exp2f(m_run - mnew);
                l_run *= r;
                #pragma unroll
                for (int dh = 0; dh < 2; ++dh)
                    #pragma unroll
                    for (int r2 = 0; r2 < 16; ++r2) acc_o[dh][r2] *= r;
                m_run = mnew;
            }
            float ps0 = 0.f, ps1 = 0.f;
            #pragma unroll
            for (int i = 0; i < 8; ++i) {
                float p0 = __builtin_amdgcn_exp2f(s[2 * i]     - m_run);
                float p1 = __builtin_amdgcn_exp2f(s[2 * i + 1] - m_run);
                ps0 += p0; ps1 += p1;
                w0[i] = pkbf(p0, p1);
            }
            float psum = ps0 + ps1;
            psum += __shfl_xor(psum, 32);
            l_run += psum;
        }

        // ---- PV half 0 (MFMA) ----
        #pragma unroll
        for (int t2 = 0; t2 < 2; ++t2) {
            u32x2 r0 = __builtin_amdgcn_permlane32_swap(w0[t2 * 4 + 0], w0[t2 * 4 + 2], false, false);
            u32x2 r1 = __builtin_amdgcn_permlane32_swap(w0[t2 * 4 + 1], w0[t2 * 4 + 3], false, false);
            u32x4 ua = (u32x4){r0[0], r1[0], r0[1], r1[1]};
            bf16x8 pa = *(bf16x8*)&ua;
            #pragma unroll
            for (int dh = 0; dh < 2; ++dh) {
                bf16x8 bv = *(const bf16x8*)&Vt[cur][dh * 32 + l31][t2 * 16 + h * 8];
                acc_o[dh] = __builtin_amdgcn_mfma_f32_32x32x16_bf16(pa, bv, acc_o[dh], 0, 0, 0);
            }
        }

        // ---- softmax half 1 (VALU; overlaps PV h0 MFMA) ----
        unsigned w1[8];
        {
            float s[16];
            float tmax = -1e30f;
            #pragma unroll
            for (int g = 0; g < 4; ++g) {
                f32x4 mk = *(const f32x4*)&maskf[kt + 32 + g * 8 + h * 4];
                #pragma unroll
                for (int j = 0; j < 4; ++j) {
                    float val = fmaf(a1[g * 4 + j], SC, mk[j]);
                    s[g * 4 + j] = val;
                    tmax = fmaxf(tmax, val);
                }
            }
            tmax = fmaxf(tmax, __shfl_xor(tmax, 32));
            if (__any(tmax > m_run + 8.0f)) {
                float mnew = fmaxf(m_run, tmax);
                float r = __builtin_amdgcn_exp2f(m_run - mnew);
                l_run *= r;
                #pragma unroll
                for (int dh = 0; dh < 2; ++dh)
                    #pragma unroll
                    for (int r2 = 0; r2 < 16; ++r2) acc_o[dh][r2] *= r;
                m_run = mnew;
            }
            float ps0 = 0.f, ps1 = 0.f;
            #pragma unroll
            for (int i = 0; i < 8; ++i) {
                float p0 = __builtin_amdgcn_exp2f(s[2 * i]     - m_run);
                float p1 = __builtin_amdgcn_exp2f(s[2 * i + 1] - m_run);
                ps0 += p0; ps1 += p1;
                w1[i] = pkbf(p0, p1);
            }
            float psum = ps0 + ps1;
            psum += __shfl_xor(psum, 32);
            l_run += psum;
        }

        // ---- PV half 1 (MFMA) ----
        #pragma unroll
        for (int t2 = 0; t2 < 2; ++t2) {
            u32x2 r0 = __builtin_amdgcn_permlane32_swap(w1[t2 * 4 + 0], w1[t2 * 4 + 2], false, false);
            u32x2 r1 = __builtin_amdgcn_permlane32_swap(w1[t2 * 4 + 1], w1[t2 * 4 + 3], false, false);
            u32x4 ua = (u32x4){r0[0], r1[0], r0[1], r1[1]};
            bf16x8 pa = *(bf16x8*)&ua;
            #pragma unroll
            for (int dh = 0; dh < 2; ++dh) {
                bf16x8 bv = *(const bf16x8*)&Vt[cur][dh * 32 + l31][32 + t2 * 16 + h * 8];
                acc_o[dh] = __builtin_amdgcn_mfma_f32_32x32x16_bf16(pa, bv, acc_o[dh], 0, 0, 0);
            }
        }

        if (t < 15) {   // write next tile into alternate buffer
            *(u32x4*)&Klds[cur ^ 1][kk][d0] = (u32x4){pkbf(kA[0], kA[1]), pkbf(kA[2], kA[3]),
                                                      pkbf(kB[0], kB[1]), pkbf(kB[2], kB[3])};
            *(u32x4*)&Vt[cur ^ 1][dcol][kr0] = (u32x4){pkbf(vv[0], vv[1]), pkbf(vv[2], vv[3]),
                                                       pkbf(vv[4], vv[5]), pkbf(vv[6], vv[7])};
        }
        cur ^= 1;
    }

    // ---- channel gate: gate[q][e] = sum_d am[q][d]*W[e][d], same C layout as O ----
    f32x16 acc_g[2];
    #pragma unroll
    for (int eh = 0; eh < 2; ++eh)
        #pragma unroll
        for (int r = 0; r < 16; ++r) acc_g[eh][r] = 0.0f;

    bf16x8 bam[4];
    #pragma unroll
    for (int ds = 0; ds < 4; ++ds) {
        const f32x4* p1 = (const f32x4*)(V1p + (size_t)qrow * D + ds * 16 + h * 8);
        const f32x4* pk = (const f32x4*)(Kp  + (size_t)qrow * D + ds * 16 + h * 8);
        f32x4 a0 = p1[0], a1 = p1[1], c0 = pk[0], c1 = pk[1];
        u32x4 u = (u32x4){pkbf(a0[0] * c0[0], a0[1] * c0[1]), pkbf(a0[2] * c0[2], a0[3] * c0[3]),
                          pkbf(a1[0] * c1[0], a1[1] * c1[1]), pkbf(a1[2] * c1[2], a1[3] * c1[3])};
        bam[ds] = *(bf16x8*)&u;
    }
    #pragma unroll
    for (int eh = 0; eh < 2; ++eh) {
        #pragma unroll
        for (int ds = 0; ds < 4; ++ds) {
            const f32x4* pw = (const f32x4*)(W + (size_t)(eh * 32 + l31) * D + ds * 16 + h * 8);
            f32x4 x0 = pw[0], x1 = pw[1];
            u32x4 u = (u32x4){pkbf(x0[0], x0[1]), pkbf(x0[2], x0[3]),
                              pkbf(x1[0], x1[1]), pkbf(x1[2], x1[3])};
            bf16x8 bw = *(bf16x8*)&u;
            acc_g[eh] = __builtin_amdgcn_mfma_f32_32x32x16_bf16(bam[ds], bw, acc_g[eh], 0, 0, 0);
        }
    }

    // ---- epilogue: out = (O/l) * sigmoid(gate + b) ----
    Lw[wid][l31] = 1.0f / l_run;
    __builtin_amdgcn_wave_barrier();
    const float bv0 = bch[l31], bv1 = bch[32 + l31];
    #pragma unroll
    for (int dh = 0; dh < 2; ++dh) {
        const float bc = dh ? bv1 : bv0;
        #pragma unroll
        for (int r = 0; r < 16; ++r) {
            const int ql = (r & 3) + 8 * (r >> 2) + 4 * h;   // crow(r,h)
            float invl = Lw[wid][ql];
            float o = acc_o[dh][r] * invl;
            float z = acc_g[dh][r] + bc;
            float gate = 1.0f / (1.0f + __expf(-z));
            out_attn[base + (size_t)(q0 + ql) * D + dh * 32 + l31] = o * gate;
        }
    }
}

extern "C" void kernel_launch(void* const* d_in, const int* in_sizes, int n_in,
                              void* d_out, int out_size, void* d_ws, size_t ws_size,
                              hipStream_t stream) {
    const float* gv   = (const float*)d_in[0];
    const float* q2   = (const float*)d_in[1];
    const float* keyp = (const float*)d_in[2];
    const int*   mask = (const int*)  d_in[3];
    const float* v1   = (const float*)d_in[4];
    const float* v2   = (const float*)d_in[5];
    const float* W    = (const float*)d_in[6];
    const float* bch  = (const float*)d_in[7];
    float* out = (float*)d_out;

    dim3 grid(64, 4);   // (b*h, 256-row q-tile) = 256 blocks = 1/CU
    aoa_attn_kernel<<<grid, 512, 0, stream>>>(gv, q2, keyp, mask, v1, v2, W, bch, out);
}